// Round 1
// baseline (34297.424 us; speedup 1.0000x reference)
//
#include <hip/hip_runtime.h>
#include <hip/hip_bf16.h>
#include <cstdint>

#define AXIS_CAP 32
#define GRID_SIZE_F 0.04f
#define BINS_PER_BATCH (AXIS_CAP * AXIS_CAP * AXIS_CAP)   // 32768
#define SCAN_TPB 256
#define BINS_PER_THREAD 4
#define BINS_PER_BLOCK (SCAN_TPB * BINS_PER_THREAD)       // 1024

__device__ __forceinline__ int point_batch(int i, const int* offs, int B) {
    // searchsorted(offset, i, side='right') == count of offsets <= i
    int b = 0;
    for (int k = 0; k < B; ++k) b += (offs[k] <= i);
    return b;
}

// ---- init scratch ----
__global__ void init_kernel(uint32_t* binCount, uint32_t* cursor, int nbins,
                            int* startBits, int B) {
    int i = blockIdx.x * blockDim.x + threadIdx.x;
    int stride = gridDim.x * blockDim.x;
    for (int v = i; v < nbins; v += stride) { binCount[v] = 0; cursor[v] = 0; }
    if (i < 3 * B) startBits[i] = 0x7F800000;  // +inf
}

// ---- per-batch min coord (positive floats: int-bit atomicMin == float min) ----
__global__ void batch_min_kernel(const float* __restrict__ coord,
                                 const int* __restrict__ offs,
                                 int B, int N, int* startBits) {
    int i = blockIdx.x * blockDim.x + threadIdx.x;
    if (i >= N) return;
    int b = point_batch(i, offs, B);
    for (int d = 0; d < 3; ++d) {
        float c = coord[(size_t)i * 3 + d];
        atomicMin(&startBits[b * 3 + d], __float_as_int(c));
    }
}

// ---- per-point voxel key + histogram ----
__global__ void keys_count_kernel(const float* __restrict__ coord,
                                  const int* __restrict__ offs,
                                  const int* __restrict__ startBits,
                                  int B, int N,
                                  uint32_t* __restrict__ keys,
                                  uint32_t* __restrict__ binCount) {
    int i = blockIdx.x * blockDim.x + threadIdx.x;
    if (i >= N) return;
    int b = point_batch(i, offs, B);
    int v[3];
    for (int d = 0; d < 3; ++d) {
        float s = __int_as_float(startBits[b * 3 + d]);
        float q = (coord[(size_t)i * 3 + d] - s) / GRID_SIZE_F;  // IEEE div, matches ref
        int vi = (int)floorf(q);
        vi = vi < 0 ? 0 : (vi > AXIS_CAP - 1 ? AXIS_CAP - 1 : vi);  // safety clamp
        v[d] = vi;
    }
    uint32_t key = ((uint32_t)b * AXIS_CAP + v[0]) * AXIS_CAP * AXIS_CAP
                 + (uint32_t)v[1] * AXIS_CAP + v[2];
    keys[i] = key;
    atomicAdd(&binCount[key], 1u);
}

// ---- scan pass 1: per-block local exclusive prefixes + block totals ----
__global__ void scan1_kernel(const uint32_t* __restrict__ binCount,
                             uint32_t* __restrict__ binStart,
                             uint32_t* __restrict__ binSeg,
                             uint32_t* __restrict__ blockCnt,
                             uint32_t* __restrict__ blockOcc) {
    __shared__ uint32_t sC[SCAN_TPB], sO[SCAN_TPB];
    int t = threadIdx.x;
    int base = blockIdx.x * BINS_PER_BLOCK + t * BINS_PER_THREAD;
    uint32_t c[BINS_PER_THREAD];
    uint32_t tc = 0, to = 0;
#pragma unroll
    for (int j = 0; j < BINS_PER_THREAD; ++j) {
        c[j] = binCount[base + j];
        tc += c[j];
        to += (c[j] > 0u);
    }
    sC[t] = tc; sO[t] = to;
    __syncthreads();
    // inclusive Hillis-Steele over 256 threads
    for (int off = 1; off < SCAN_TPB; off <<= 1) {
        uint32_t a = 0, b2 = 0;
        if (t >= off) { a = sC[t - off]; b2 = sO[t - off]; }
        __syncthreads();
        sC[t] += a; sO[t] += b2;
        __syncthreads();
    }
    uint32_t exC = sC[t] - tc;
    uint32_t exO = sO[t] - to;
#pragma unroll
    for (int j = 0; j < BINS_PER_THREAD; ++j) {
        binStart[base + j] = exC;
        binSeg[base + j] = exO;
        exC += c[j];
        exO += (c[j] > 0u);
    }
    if (t == SCAN_TPB - 1) {
        blockCnt[blockIdx.x] = sC[t];
        blockOcc[blockIdx.x] = sO[t];
    }
}

// ---- scan pass 2: single block scans block totals (exclusive, in place) ----
__global__ void scan2_kernel(uint32_t* blockCnt, uint32_t* blockOcc,
                             uint32_t* totals, int nb) {
    __shared__ uint32_t sC[SCAN_TPB], sO[SCAN_TPB];
    int t = threadIdx.x;
    uint32_t c = (t < nb) ? blockCnt[t] : 0u;
    uint32_t o = (t < nb) ? blockOcc[t] : 0u;
    sC[t] = c; sO[t] = o;
    __syncthreads();
    for (int off = 1; off < SCAN_TPB; off <<= 1) {
        uint32_t a = 0, b2 = 0;
        if (t >= off) { a = sC[t - off]; b2 = sO[t - off]; }
        __syncthreads();
        sC[t] += a; sO[t] += b2;
        __syncthreads();
    }
    if (t < nb) { blockCnt[t] = sC[t] - c; blockOcc[t] = sO[t] - o; }
    if (t == SCAN_TPB - 1) { totals[0] = sO[t]; totals[1] = sC[t]; }
}

// ---- scan pass 3: add block offsets ----
__global__ void scan3_kernel(uint32_t* __restrict__ binStart,
                             uint32_t* __restrict__ binSeg,
                             const uint32_t* __restrict__ blockCnt,
                             const uint32_t* __restrict__ blockOcc) {
    int t = threadIdx.x;
    int base = blockIdx.x * BINS_PER_BLOCK + t * BINS_PER_THREAD;
    uint32_t oc = blockCnt[blockIdx.x];
    uint32_t oo = blockOcc[blockIdx.x];
#pragma unroll
    for (int j = 0; j < BINS_PER_THREAD; ++j) {
        binStart[base + j] += oc;
        binSeg[base + j] += oo;
    }
}

// ---- scatter point indices into per-voxel contiguous runs ----
__global__ void scatter_kernel(const uint32_t* __restrict__ keys,
                               const uint32_t* __restrict__ binStart,
                               uint32_t* __restrict__ cursor,
                               uint32_t* __restrict__ pointIdx, int N) {
    int i = blockIdx.x * blockDim.x + threadIdx.x;
    if (i >= N) return;
    uint32_t key = keys[i];
    uint32_t pos = binStart[key] + atomicAdd(&cursor[key], 1u);
    pointIdx[pos] = (uint32_t)i;
}

// ---- per-voxel reduction: one 64-thread wave per bin ----
__global__ __launch_bounds__(64) void reduce_kernel(
        const float* __restrict__ coord, const float* __restrict__ feat,
        const uint32_t* __restrict__ binCount,
        const uint32_t* __restrict__ binStart,
        const uint32_t* __restrict__ binSeg,
        const uint32_t* __restrict__ pointIdx,
        float* __restrict__ out, int N, int C) {
    int bin = blockIdx.x;
    uint32_t cnt = binCount[bin];
    if (cnt == 0u) return;
    uint32_t st = binStart[bin];
    uint32_t seg = binSeg[bin];
    int lane = threadIdx.x;

    // feat max: lane = channel (C==64), coalesced row reads
    float* feat_out = out + (size_t)N * 3;
    for (int c = lane; c < C; c += 64) {
        float m = -INFINITY;
        for (uint32_t p = 0; p < cnt; ++p) {
            uint32_t idx = pointIdx[st + p];
            m = fmaxf(m, feat[(size_t)idx * C + c]);
        }
        feat_out[(size_t)seg * C + c] = m;
    }

    // coord mean: lane-parallel over points, shuffle reduce
    float sx = 0.f, sy = 0.f, sz = 0.f;
    for (uint32_t p = lane; p < cnt; p += 64) {
        uint32_t idx = pointIdx[st + p];
        sx += coord[(size_t)idx * 3 + 0];
        sy += coord[(size_t)idx * 3 + 1];
        sz += coord[(size_t)idx * 3 + 2];
    }
    for (int off = 32; off > 0; off >>= 1) {
        sx += __shfl_down(sx, off);
        sy += __shfl_down(sy, off);
        sz += __shfl_down(sz, off);
    }
    if (lane == 0) {
        float inv = 1.0f / (float)cnt;
        out[(size_t)seg * 3 + 0] = sx * inv;
        out[(size_t)seg * 3 + 1] = sy * inv;
        out[(size_t)seg * 3 + 2] = sz * inv;
    }
}

// ---- zero padding rows >= n_vox ----
__global__ void pad_kernel(float* __restrict__ out,
                           const uint32_t* __restrict__ totals, int N, int C) {
    uint32_t nvox = totals[0];
    size_t gid = (size_t)blockIdx.x * blockDim.x + threadIdx.x;
    size_t stride = (size_t)gridDim.x * blockDim.x;
    float* featBase = out + (size_t)N * 3;
    if ((C & 3) == 0) {
        float4* f4 = (float4*)featBase;
        size_t r4 = (size_t)C / 4;
        size_t v0 = (size_t)nvox * r4, v1 = (size_t)N * r4;
        for (size_t v = v0 + gid; v < v1; v += stride)
            f4[v] = make_float4(0.f, 0.f, 0.f, 0.f);
    } else {
        size_t e0 = (size_t)nvox * C, e1 = (size_t)N * C;
        for (size_t e = e0 + gid; e < e1; e += stride) featBase[e] = 0.f;
    }
    for (size_t r = nvox + gid; r < (size_t)N; r += stride) {
        out[r * 3 + 0] = 0.f;
        out[r * 3 + 1] = 0.f;
        out[r * 3 + 2] = 0.f;
    }
}

// ---- offset_out + n_vox (written as float32 into the flat output) ----
__global__ void finalize_kernel(const uint32_t* __restrict__ binSeg,
                                const uint32_t* __restrict__ totals,
                                float* __restrict__ out, int B, int N, int C) {
    int t = threadIdx.x;
    uint32_t nvox = totals[0];
    float* tail = out + (size_t)N * 3 + (size_t)N * C;  // offset_out then n_vox
    if (t < B) {
        uint32_t v = (t == B - 1) ? nvox
                                  : binSeg[(size_t)(t + 1) * BINS_PER_BATCH];
        tail[t] = (float)v;
    }
    if (t == 0) tail[B] = (float)nvox;
}

extern "C" void kernel_launch(void* const* d_in, const int* in_sizes, int n_in,
                              void* d_out, int out_size, void* d_ws, size_t ws_size,
                              hipStream_t stream) {
    const float* coord = (const float*)d_in[0];
    const float* feat  = (const float*)d_in[1];
    const int*   offs  = (const int*)d_in[2];
    float* out = (float*)d_out;

    int N = in_sizes[0] / 3;
    int C = in_sizes[1] / N;
    int B = in_sizes[2];
    int NBINS = B * BINS_PER_BATCH;          // 131072 for B=4
    int NB1 = NBINS / BINS_PER_BLOCK;        // 128

    // workspace layout
    uint8_t* w = (uint8_t*)d_ws;
    uint32_t* binCount = (uint32_t*)w;              w += (size_t)NBINS * 4;
    uint32_t* binStart = (uint32_t*)w;              w += (size_t)NBINS * 4;
    uint32_t* binSeg   = (uint32_t*)w;              w += (size_t)NBINS * 4;
    uint32_t* cursor   = (uint32_t*)w;              w += (size_t)NBINS * 4;
    uint32_t* blockCnt = (uint32_t*)w;              w += (size_t)NB1 * 4;
    uint32_t* blockOcc = (uint32_t*)w;              w += (size_t)NB1 * 4;
    uint32_t* totals   = (uint32_t*)w;              w += 2 * 4;
    int*      startBits= (int*)w;                   w += (size_t)3 * B * 4 + 8;
    uint32_t* keys     = (uint32_t*)w;              w += (size_t)N * 4;
    uint32_t* pointIdx = (uint32_t*)w;              /* w += N*4 */

    int ptBlocks = (N + 255) / 256;

    init_kernel<<<512, 256, 0, stream>>>(binCount, cursor, NBINS, startBits, B);
    batch_min_kernel<<<ptBlocks, 256, 0, stream>>>(coord, offs, B, N, startBits);
    keys_count_kernel<<<ptBlocks, 256, 0, stream>>>(coord, offs, startBits, B, N,
                                                    keys, binCount);
    scan1_kernel<<<NB1, SCAN_TPB, 0, stream>>>(binCount, binStart, binSeg,
                                               blockCnt, blockOcc);
    scan2_kernel<<<1, SCAN_TPB, 0, stream>>>(blockCnt, blockOcc, totals, NB1);
    scan3_kernel<<<NB1, SCAN_TPB, 0, stream>>>(binStart, binSeg, blockCnt, blockOcc);
    scatter_kernel<<<ptBlocks, 256, 0, stream>>>(keys, binStart, cursor, pointIdx, N);
    reduce_kernel<<<NBINS, 64, 0, stream>>>(coord, feat, binCount, binStart,
                                            binSeg, pointIdx, out, N, C);
    pad_kernel<<<2048, 256, 0, stream>>>(out, totals, N, C);
    finalize_kernel<<<1, 64, 0, stream>>>(binSeg, totals, out, B, N, C);
}

// Round 2
// 306.395 us; speedup vs baseline: 111.9386x; 111.9386x over previous
//
#include <hip/hip_runtime.h>
#include <hip/hip_bf16.h>
#include <cstdint>

#define AXIS_CAP 32
#define GRID_SIZE_F 0.04f
#define BINS_PER_BATCH (AXIS_CAP * AXIS_CAP * AXIS_CAP)   // 32768
#define SCAN_TPB 256
#define BINS_PER_THREAD 4
#define BINS_PER_BLOCK (SCAN_TPB * BINS_PER_THREAD)       // 1024

__device__ __forceinline__ int point_batch(int i, const int* offs, int B) {
    // searchsorted(offset, i, side='right') == count of offsets <= i
    int b = 0;
    for (int k = 0; k < B; ++k) b += (offs[k] <= i);
    return b;
}

// ---- init scratch ----
__global__ void init_kernel(uint32_t* binCount, uint32_t* cursor, int nbins,
                            int* startBits, int B) {
    int i = blockIdx.x * blockDim.x + threadIdx.x;
    int stride = gridDim.x * blockDim.x;
    for (int v = i; v < nbins; v += stride) { binCount[v] = 0; cursor[v] = 0; }
    if (i < 3 * B) startBits[i] = 0x7F800000;  // +inf
}

// ---- per-batch min coord, hierarchical: reg -> wave shuffle -> LDS -> global ----
// Handles B <= 4 with fully-unrolled register accumulators (compile-time
// indices, no scratch). Coords are non-negative floats so int-bit min ==
// float min.
__global__ __launch_bounds__(256) void batch_min4_kernel(
        const float* __restrict__ coord, const int* __restrict__ offs,
        int B, int N, int* __restrict__ startBits) {
    __shared__ int smin[12];
    if (threadIdx.x < 12) smin[threadIdx.x] = 0x7F800000;
    __syncthreads();

    int o0 = offs[0];
    int o1 = (B > 1) ? offs[1] : o0;
    int o2 = (B > 2) ? offs[2] : o1;

    float m[4][3];
#pragma unroll
    for (int bb = 0; bb < 4; ++bb)
#pragma unroll
        for (int d = 0; d < 3; ++d) m[bb][d] = INFINITY;

    int gid = blockIdx.x * blockDim.x + threadIdx.x;
    int stride = gridDim.x * blockDim.x;
    for (int i = gid; i < N; i += stride) {
        float x = coord[(size_t)i * 3 + 0];
        float y = coord[(size_t)i * 3 + 1];
        float z = coord[(size_t)i * 3 + 2];
        int b = (i >= o0) + (i >= o1) + (i >= o2);
#pragma unroll
        for (int bb = 0; bb < 4; ++bb) {
            bool sel = (bb == b);
            m[bb][0] = fminf(m[bb][0], sel ? x : INFINITY);
            m[bb][1] = fminf(m[bb][1], sel ? y : INFINITY);
            m[bb][2] = fminf(m[bb][2], sel ? z : INFINITY);
        }
    }

    // wave butterfly reduce (64 lanes)
#pragma unroll
    for (int bb = 0; bb < 4; ++bb)
#pragma unroll
        for (int d = 0; d < 3; ++d) {
            float v = m[bb][d];
            for (int off = 32; off > 0; off >>= 1)
                v = fminf(v, __shfl_xor(v, off));
            m[bb][d] = v;
        }

    if ((threadIdx.x & 63) == 0) {
#pragma unroll
        for (int bb = 0; bb < 4; ++bb)
#pragma unroll
            for (int d = 0; d < 3; ++d)
                atomicMin(&smin[bb * 3 + d], __float_as_int(m[bb][d]));
    }
    __syncthreads();
    if (threadIdx.x < 12 && (threadIdx.x / 3) < B)
        atomicMin(&startBits[threadIdx.x], smin[threadIdx.x]);
}

// ---- generic fallback for B > 4 (per-wave atomics; rare path) ----
__global__ void batch_min_generic_kernel(const float* __restrict__ coord,
                                         const int* __restrict__ offs,
                                         int B, int N, int* startBits) {
    int i = blockIdx.x * blockDim.x + threadIdx.x;
    if (i >= N) return;
    int b = point_batch(i, offs, B);
    for (int d = 0; d < 3; ++d) {
        float c = coord[(size_t)i * 3 + d];
        atomicMin(&startBits[b * 3 + d], __float_as_int(c));
    }
}

// ---- per-point voxel key + histogram ----
__global__ void keys_count_kernel(const float* __restrict__ coord,
                                  const int* __restrict__ offs,
                                  const int* __restrict__ startBits,
                                  int B, int N,
                                  uint32_t* __restrict__ keys,
                                  uint32_t* __restrict__ binCount) {
    int i = blockIdx.x * blockDim.x + threadIdx.x;
    if (i >= N) return;
    int b = point_batch(i, offs, B);
    int v[3];
    for (int d = 0; d < 3; ++d) {
        float s = __int_as_float(startBits[b * 3 + d]);
        float q = (coord[(size_t)i * 3 + d] - s) / GRID_SIZE_F;  // IEEE div, matches ref
        int vi = (int)floorf(q);
        vi = vi < 0 ? 0 : (vi > AXIS_CAP - 1 ? AXIS_CAP - 1 : vi);  // safety clamp
        v[d] = vi;
    }
    uint32_t key = ((uint32_t)b * AXIS_CAP + v[0]) * AXIS_CAP * AXIS_CAP
                 + (uint32_t)v[1] * AXIS_CAP + v[2];
    keys[i] = key;
    atomicAdd(&binCount[key], 1u);
}

// ---- scan pass 1: per-block local exclusive prefixes + block totals ----
__global__ void scan1_kernel(const uint32_t* __restrict__ binCount,
                             uint32_t* __restrict__ binStart,
                             uint32_t* __restrict__ binSeg,
                             uint32_t* __restrict__ blockCnt,
                             uint32_t* __restrict__ blockOcc) {
    __shared__ uint32_t sC[SCAN_TPB], sO[SCAN_TPB];
    int t = threadIdx.x;
    int base = blockIdx.x * BINS_PER_BLOCK + t * BINS_PER_THREAD;
    uint32_t c[BINS_PER_THREAD];
    uint32_t tc = 0, to = 0;
#pragma unroll
    for (int j = 0; j < BINS_PER_THREAD; ++j) {
        c[j] = binCount[base + j];
        tc += c[j];
        to += (c[j] > 0u);
    }
    sC[t] = tc; sO[t] = to;
    __syncthreads();
    // inclusive Hillis-Steele over 256 threads
    for (int off = 1; off < SCAN_TPB; off <<= 1) {
        uint32_t a = 0, b2 = 0;
        if (t >= off) { a = sC[t - off]; b2 = sO[t - off]; }
        __syncthreads();
        sC[t] += a; sO[t] += b2;
        __syncthreads();
    }
    uint32_t exC = sC[t] - tc;
    uint32_t exO = sO[t] - to;
#pragma unroll
    for (int j = 0; j < BINS_PER_THREAD; ++j) {
        binStart[base + j] = exC;
        binSeg[base + j] = exO;
        exC += c[j];
        exO += (c[j] > 0u);
    }
    if (t == SCAN_TPB - 1) {
        blockCnt[blockIdx.x] = sC[t];
        blockOcc[blockIdx.x] = sO[t];
    }
}

// ---- scan pass 2: single block scans block totals (exclusive, in place) ----
__global__ void scan2_kernel(uint32_t* blockCnt, uint32_t* blockOcc,
                             uint32_t* totals, int nb) {
    __shared__ uint32_t sC[SCAN_TPB], sO[SCAN_TPB];
    int t = threadIdx.x;
    uint32_t c = (t < nb) ? blockCnt[t] : 0u;
    uint32_t o = (t < nb) ? blockOcc[t] : 0u;
    sC[t] = c; sO[t] = o;
    __syncthreads();
    for (int off = 1; off < SCAN_TPB; off <<= 1) {
        uint32_t a = 0, b2 = 0;
        if (t >= off) { a = sC[t - off]; b2 = sO[t - off]; }
        __syncthreads();
        sC[t] += a; sO[t] += b2;
        __syncthreads();
    }
    if (t < nb) { blockCnt[t] = sC[t] - c; blockOcc[t] = sO[t] - o; }
    if (t == SCAN_TPB - 1) { totals[0] = sO[t]; totals[1] = sC[t]; }
}

// ---- scan pass 3: add block offsets ----
__global__ void scan3_kernel(uint32_t* __restrict__ binStart,
                             uint32_t* __restrict__ binSeg,
                             const uint32_t* __restrict__ blockCnt,
                             const uint32_t* __restrict__ blockOcc) {
    int t = threadIdx.x;
    int base = blockIdx.x * BINS_PER_BLOCK + t * BINS_PER_THREAD;
    uint32_t oc = blockCnt[blockIdx.x];
    uint32_t oo = blockOcc[blockIdx.x];
#pragma unroll
    for (int j = 0; j < BINS_PER_THREAD; ++j) {
        binStart[base + j] += oc;
        binSeg[base + j] += oo;
    }
}

// ---- scatter point indices into per-voxel contiguous runs ----
__global__ void scatter_kernel(const uint32_t* __restrict__ keys,
                               const uint32_t* __restrict__ binStart,
                               uint32_t* __restrict__ cursor,
                               uint32_t* __restrict__ pointIdx, int N) {
    int i = blockIdx.x * blockDim.x + threadIdx.x;
    if (i >= N) return;
    uint32_t key = keys[i];
    uint32_t pos = binStart[key] + atomicAdd(&cursor[key], 1u);
    pointIdx[pos] = (uint32_t)i;
}

// ---- per-voxel reduction: one 64-thread wave per bin ----
__global__ __launch_bounds__(64) void reduce_kernel(
        const float* __restrict__ coord, const float* __restrict__ feat,
        const uint32_t* __restrict__ binCount,
        const uint32_t* __restrict__ binStart,
        const uint32_t* __restrict__ binSeg,
        const uint32_t* __restrict__ pointIdx,
        float* __restrict__ out, int N, int C) {
    int bin = blockIdx.x;
    uint32_t cnt = binCount[bin];
    if (cnt == 0u) return;
    uint32_t st = binStart[bin];
    uint32_t seg = binSeg[bin];
    int lane = threadIdx.x;

    // feat max: lane = channel (C==64), coalesced row reads
    float* feat_out = out + (size_t)N * 3;
    for (int c = lane; c < C; c += 64) {
        float m = -INFINITY;
        for (uint32_t p = 0; p < cnt; ++p) {
            uint32_t idx = pointIdx[st + p];
            m = fmaxf(m, feat[(size_t)idx * C + c]);
        }
        feat_out[(size_t)seg * C + c] = m;
    }

    // coord mean: lane-parallel over points, shuffle reduce
    float sx = 0.f, sy = 0.f, sz = 0.f;
    for (uint32_t p = lane; p < cnt; p += 64) {
        uint32_t idx = pointIdx[st + p];
        sx += coord[(size_t)idx * 3 + 0];
        sy += coord[(size_t)idx * 3 + 1];
        sz += coord[(size_t)idx * 3 + 2];
    }
    for (int off = 32; off > 0; off >>= 1) {
        sx += __shfl_down(sx, off);
        sy += __shfl_down(sy, off);
        sz += __shfl_down(sz, off);
    }
    if (lane == 0) {
        float inv = 1.0f / (float)cnt;
        out[(size_t)seg * 3 + 0] = sx * inv;
        out[(size_t)seg * 3 + 1] = sy * inv;
        out[(size_t)seg * 3 + 2] = sz * inv;
    }
}

// ---- zero padding rows >= n_vox ----
__global__ void pad_kernel(float* __restrict__ out,
                           const uint32_t* __restrict__ totals, int N, int C) {
    uint32_t nvox = totals[0];
    size_t gid = (size_t)blockIdx.x * blockDim.x + threadIdx.x;
    size_t stride = (size_t)gridDim.x * blockDim.x;
    float* featBase = out + (size_t)N * 3;
    if ((C & 3) == 0) {
        float4* f4 = (float4*)featBase;
        size_t r4 = (size_t)C / 4;
        size_t v0 = (size_t)nvox * r4, v1 = (size_t)N * r4;
        for (size_t v = v0 + gid; v < v1; v += stride)
            f4[v] = make_float4(0.f, 0.f, 0.f, 0.f);
    } else {
        size_t e0 = (size_t)nvox * C, e1 = (size_t)N * C;
        for (size_t e = e0 + gid; e < e1; e += stride) featBase[e] = 0.f;
    }
    for (size_t r = nvox + gid; r < (size_t)N; r += stride) {
        out[r * 3 + 0] = 0.f;
        out[r * 3 + 1] = 0.f;
        out[r * 3 + 2] = 0.f;
    }
}

// ---- offset_out + n_vox (written as float32 into the flat output) ----
__global__ void finalize_kernel(const uint32_t* __restrict__ binSeg,
                                const uint32_t* __restrict__ totals,
                                float* __restrict__ out, int B, int N, int C) {
    int t = threadIdx.x;
    uint32_t nvox = totals[0];
    float* tail = out + (size_t)N * 3 + (size_t)N * C;  // offset_out then n_vox
    if (t < B) {
        uint32_t v = (t == B - 1) ? nvox
                                  : binSeg[(size_t)(t + 1) * BINS_PER_BATCH];
        tail[t] = (float)v;
    }
    if (t == 0) tail[B] = (float)nvox;
}

extern "C" void kernel_launch(void* const* d_in, const int* in_sizes, int n_in,
                              void* d_out, int out_size, void* d_ws, size_t ws_size,
                              hipStream_t stream) {
    const float* coord = (const float*)d_in[0];
    const float* feat  = (const float*)d_in[1];
    const int*   offs  = (const int*)d_in[2];
    float* out = (float*)d_out;

    int N = in_sizes[0] / 3;
    int C = in_sizes[1] / N;
    int B = in_sizes[2];
    int NBINS = B * BINS_PER_BATCH;          // 131072 for B=4
    int NB1 = NBINS / BINS_PER_BLOCK;        // 128

    // workspace layout
    uint8_t* w = (uint8_t*)d_ws;
    uint32_t* binCount = (uint32_t*)w;              w += (size_t)NBINS * 4;
    uint32_t* binStart = (uint32_t*)w;              w += (size_t)NBINS * 4;
    uint32_t* binSeg   = (uint32_t*)w;              w += (size_t)NBINS * 4;
    uint32_t* cursor   = (uint32_t*)w;              w += (size_t)NBINS * 4;
    uint32_t* blockCnt = (uint32_t*)w;              w += (size_t)NB1 * 4;
    uint32_t* blockOcc = (uint32_t*)w;              w += (size_t)NB1 * 4;
    uint32_t* totals   = (uint32_t*)w;              w += 2 * 4;
    int*      startBits= (int*)w;                   w += (size_t)3 * B * 4 + 8;
    uint32_t* keys     = (uint32_t*)w;              w += (size_t)N * 4;
    uint32_t* pointIdx = (uint32_t*)w;              /* w += N*4 */

    int ptBlocks = (N + 255) / 256;

    init_kernel<<<512, 256, 0, stream>>>(binCount, cursor, NBINS, startBits, B);
    if (B <= 4) {
        batch_min4_kernel<<<1024, 256, 0, stream>>>(coord, offs, B, N, startBits);
    } else {
        batch_min_generic_kernel<<<ptBlocks, 256, 0, stream>>>(coord, offs, B, N,
                                                               startBits);
    }
    keys_count_kernel<<<ptBlocks, 256, 0, stream>>>(coord, offs, startBits, B, N,
                                                    keys, binCount);
    scan1_kernel<<<NB1, SCAN_TPB, 0, stream>>>(binCount, binStart, binSeg,
                                               blockCnt, blockOcc);
    scan2_kernel<<<1, SCAN_TPB, 0, stream>>>(blockCnt, blockOcc, totals, NB1);
    scan3_kernel<<<NB1, SCAN_TPB, 0, stream>>>(binStart, binSeg, blockCnt, blockOcc);
    scatter_kernel<<<ptBlocks, 256, 0, stream>>>(keys, binStart, cursor, pointIdx, N);
    reduce_kernel<<<NBINS, 64, 0, stream>>>(coord, feat, binCount, binStart,
                                            binSeg, pointIdx, out, N, C);
    pad_kernel<<<2048, 256, 0, stream>>>(out, totals, N, C);
    finalize_kernel<<<1, 64, 0, stream>>>(binSeg, totals, out, B, N, C);
}